// Round 7
// baseline (1555.689 us; speedup 1.0000x reference)
//
#include <hip/hip_runtime.h>
#include <hip/hip_bf16.h>
#include <math.h>

typedef long long ll;
typedef __attribute__((ext_vector_type(8))) short s8v;
typedef __attribute__((ext_vector_type(4))) float f4v;
typedef __attribute__((address_space(1))) unsigned int gu32;
typedef __attribute__((address_space(3))) unsigned int lu32;

#define NPOS 3072
// state z layout: [0]=dq_b0 [1]=dq_b1 [2]=d3_b0 [3]=d3_b1
// ALL activations position-major: [z][n][c]

// ---------------- workspace offsets (floats) ----------------
#define OFF_STF   0LL          /* fp32 state [4][3072][256] */
#define OFF_STB   3145728LL    /* bf16 state (shorts) */
#define OFF_QKV   4718592LL    /* bf16 [4][3072][768] shorts */
#define OFF_MSG   9437184LL    /* bf16 [4][3072][256] shorts; obuf + finbf alias */
#define OFF_HID   11010048LL   /* bf16 [4][3072][512] shorts */
#define OFF_WBF   14155776LL   /* bf16 weights, 5,570,560 shorts */
#define OFF_PBP   16941056LL   /* permuted projb fp32 [8][768] */
#define OFF_UVEC  17026048LL
#define OFF_E2ALL 17028096LL   /* [4][2][24576] */
#define OFF_PMAX  17300480LL
#define OFF_PSUM  17595392LL
#define OFF_CMAX  17890304LL
#define OFF_CSUM  17896448LL
#define OFF_CAPV  17902592LL
#define OFF_CAPI  17976320LL
#define OFF_I0    18050048LL
#define OFF_M0    18053120LL
#define OFF_I1    18056192LL
#define OFF_M1B   18059264LL   /* bf16 [8][512][256] shorts (mlp1w second half) */
#define OFF_B1C   18583552LL   /* fp32 [8][512] folded mlp1 bias */
#define OFF_INAT  18587648LL   /* fp32 [8][4][512][2] instnorm atomic sums */
#define OFF_SVSQ  18620416LL   /* fp32 [4][3072] fin row sumsq */
#define OFF_KVAT  18632704LL   /* fp32 [8][16][4096] kv atomic */
#define OFF_KSAT  19156992LL   /* fp32 [8][16][64] ksum atomic */
#define ZERO_N    577536LL     /* floats from OFF_INAT to end of KSAT */

__device__ __forceinline__ float b2f(short s) {
  union { unsigned u; float f; } c;
  c.u = ((unsigned)(unsigned short)s) << 16;
  return c.f;
}
__device__ __forceinline__ short f2b(float f) {
  __hip_bfloat16 h = __float2bfloat16(f);
  union { __hip_bfloat16 h; short s; } c; c.h = h; return c.s;
}
__device__ __forceinline__ unsigned pk2(float a, float b) {
  return (unsigned)(unsigned short)f2b(a) | ((unsigned)(unsigned short)f2b(b) << 16);
}
__device__ __forceinline__ float waveSum(float v) {
#pragma unroll
  for (int off = 32; off > 0; off >>= 1) v += __shfl_down(v, off);
  return v;
}
// async 16B global->LDS DMA (dest must be wave-uniform base + lane*16, linear)
__device__ __forceinline__ void gld16(const short* g, short* l) {
  __builtin_amdgcn_global_load_lds((const gu32*)g, (lu32*)l, 16, 0, 0);
}
template<int N> __device__ __forceinline__ void wvm() {
  asm volatile("s_waitcnt vmcnt(%0)" :: "n"(N) : "memory");
}
__device__ __forceinline__ void wlgk0() {
  asm volatile("s_waitcnt lgkmcnt(0)" ::: "memory");
}

// ------------------------------------------------------------------
// bf16 MFMA GEMM, position-major: C[i][j] = act(alpha*sum_k A[i][k]B[j][k]
//   (*rs[i]*cs[j]) + bias[j] + R[i][j])
// Depth-2 pipeline, 3 LDS buffers, counted vmcnt, SINGLE barrier per
// K-step: {wvm<LPT> (tile kt landed), wlgk0 (own reads drained), barrier,
// stage(kt+2), reads+MFMA}. Buffer-overwrite safety: stage into buf B at
// iter kt happens after barrier kt; last reads of B (iter kt-1) were
// drained by each wave's wlgk0 before it arrived at barrier kt.
// XOR chunk swizzle on global source; same XOR on read -> 2-way (free).
// jq/zaq: blocks with blockIdx.x < jq use za=zaq (merged cross-attn qkv).
// SMODE epilogue stat fusion:
//   1: per-column online (max, sumexp) -> sp0/sp1[(z*gridY+by)*TOTJ + j]
//   2: per-column (sum, sumsq) -> atomicAdd sp0[(z*TOTJ + j)*2 + {0,1}]
//   3: per-row sumsq -> atomicAdd sp0[z*NPOS + i]
// rsmode=1: rs/cs hold sumsq; apply 1/max(sqrt(s),1e-12).
// ------------------------------------------------------------------
template<int BI, int BJ, int KT, int SMODE>
__global__ __launch_bounds__(256) void bgemm_k(
    const short* __restrict__ A, const short* __restrict__ A2, int KS,
    int lda, int lda2,
    const short* __restrict__ B,
    const float* __restrict__ bias, const float* __restrict__ R,
    float* __restrict__ C, short* __restrict__ C2,
    const float* __restrict__ rs, const float* __restrict__ cs,
    int ldc, float alpha,
    ll aB, ll a2B, ll bB, ll rB, ll cB, ll c2B,
    int za, int zbo, int act, int zand, int jq, int zaq,
    float* __restrict__ sp0, float* __restrict__ sp1, int rsmode)
{
  constexpr int NT = KT / 32;
  constexpr int WI = (BI == 128) ? 2 : 1;
  constexpr int JW = BJ / (4 / WI);
  constexpr int FI = (BI / WI) / 16;
  constexpr int FJ = JW / 16;
  constexpr int SA = BI / 64, SB = BJ / 64;
  constexpr int LPT = SA + SB;
  __shared__ __align__(16) short As[3][BI * 32];
  __shared__ __align__(16) short Bs[3][BJ * 32];
  const int z = blockIdx.z;
  const int zae = (jq > 0 && (int)blockIdx.x < jq) ? zaq : za;
  const int zA = (z + zae) & zand, zB = (z + zbo) & zand;
  const int j0 = blockIdx.x * BJ, i0 = blockIdx.y * BI;
  const int t = threadIdx.x;
  const int lane = t & 63, w = t >> 6;
  const int wi = (WI == 2) ? (w & 1) * 64 : 0;
  const int wj = (WI == 2) ? (w >> 1) * JW : w * JW;
  const int fr = lane & 15;
  const int cl = lane >> 4;
  const int r4 = cl * 4;

  const short* baseA[SA]; const short* baseA2[SA]; const short* baseB[SB];
  int slA[SA], slB[SB];
  {
    const short* Az = A + (ll)zA * aB;
    const short* A2z = A2 ? A2 + (ll)zA * a2B : nullptr;
    const short* Bz = B + (ll)zB * bB;
#pragma unroll
    for (int i = 0; i < SA; ++i) {
      int cc = t + i * 256;
      int r = cc >> 2;
      int sq = ((cc & 3) ^ ((r >> 1) & 3)) << 3;
      baseA[i] = Az + (ll)(i0 + r) * lda + sq;
      baseA2[i] = A2 ? A2z + (ll)(i0 + r) * lda2 + sq : nullptr;
      slA[i] = cc << 3;
    }
#pragma unroll
    for (int i = 0; i < SB; ++i) {
      int cc = t + i * 256;
      int r = cc >> 2;
      int sq = ((cc & 3) ^ ((r >> 1) & 3)) << 3;
      baseB[i] = Bz + (ll)(j0 + r) * KT + sq;
      slB[i] = cc << 3;
    }
  }
  int offA[FI], offB[FJ];
#pragma unroll
  for (int im = 0; im < FI; ++im) {
    int ra = wi + im * 16 + fr;
    offA[im] = ra * 32 + ((cl ^ ((ra >> 1) & 3)) << 3);
  }
#pragma unroll
  for (int in = 0; in < FJ; ++in) {
    int rb = wj + in * 16 + fr;
    offB[in] = rb * 32 + ((cl ^ ((rb >> 1) & 3)) << 3);
  }

  f4v acc[FI][FJ];
#pragma unroll
  for (int i = 0; i < FI; ++i)
#pragma unroll
    for (int j = 0; j < FJ; ++j) acc[i][j] = (f4v)0.f;

  auto stage = [&](int tile, int bi_) {
    const int k0 = tile * 32;
    short* dA = As[bi_]; short* dB = Bs[bi_];
    if (A2 && k0 >= KS) {
#pragma unroll
      for (int i = 0; i < SA; ++i) gld16(baseA2[i] + (k0 - KS), dA + slA[i]);
    } else {
#pragma unroll
      for (int i = 0; i < SA; ++i) gld16(baseA[i] + k0, dA + slA[i]);
    }
#pragma unroll
    for (int i = 0; i < SB; ++i) gld16(baseB[i] + k0, dB + slB[i]);
  };

  stage(0, 0);
  stage(1, 1);
#pragma unroll
  for (int kt = 0; kt < NT; ++kt) {
    if (kt + 1 < NT) { wvm<LPT>(); } else { wvm<0>(); }
    wlgk0();
    __builtin_amdgcn_s_barrier();
    asm volatile("" ::: "memory");
    if (kt + 2 < NT) stage(kt + 2, (kt + 2) % 3);
    const short* Ac = As[kt % 3]; const short* Bc = Bs[kt % 3];
    s8v af[FI], bfr[FJ];
#pragma unroll
    for (int im = 0; im < FI; ++im) af[im] = *(const s8v*)(Ac + offA[im]);
#pragma unroll
    for (int in = 0; in < FJ; ++in) bfr[in] = *(const s8v*)(Bc + offB[in]);
#pragma unroll
    for (int im = 0; im < FI; ++im)
#pragma unroll
      for (int in = 0; in < FJ; ++in)
        acc[im][in] = __builtin_amdgcn_mfma_f32_16x16x32_bf16(
            af[im], bfr[in], acc[im][in], 0, 0, 0);
  }

  // epilogue
  float* Cz = C ? C + (ll)z * cB : nullptr;
  short* C2z = C2 ? C2 + (ll)z * c2B : nullptr;
  const float* Rz = R ? R + (ll)z * rB : nullptr;
  const float* rsz = rs ? rs + (ll)z * NPOS : nullptr;
  float bv4[FJ], cv4[FJ];
#pragma unroll
  for (int in = 0; in < FJ; ++in) {
    int j = j0 + wj + in * 16 + fr;
    bv4[in] = bias ? bias[j] : 0.f;
    cv4[in] = cs ? cs[(ll)zB * NPOS + j] : 1.f;
    if (rsmode) cv4[in] = 1.f / fmaxf(sqrtf(cv4[in]), 1e-12f);
  }
  float stM[FJ], stS[FJ], stQ[FJ];
#pragma unroll
  for (int in = 0; in < FJ; ++in) { stM[in] = -3.4e38f; stS[in] = 0.f; stQ[in] = 0.f; }

#pragma unroll
  for (int im = 0; im < FI; ++im) {
#pragma unroll
    for (int r = 0; r < 4; ++r) {
      int i = i0 + wi + im * 16 + r4 + r;
      float rsv = rsz ? rsz[i] : 1.f;
      if (rsmode) rsv = 1.f / fmaxf(sqrtf(rsv), 1e-12f);
      int rowo = i * ldc;
      float rq3 = 0.f;
#pragma unroll
      for (int in = 0; in < FJ; ++in) {
        int j = j0 + wj + in * 16 + fr;
        float v = acc[im][in][r] * alpha;
        if (rsz) v = v * rsv * cv4[in];
        v += bv4[in];
        int off = rowo + j;
        if (Rz) v += Rz[off];
        if (act) v = v > 0.f ? v : (expf(v) - 1.f);
        if constexpr (SMODE == 1) {
          float m = stM[in];
          if (v > m) { stS[in] = stS[in] * expf(m - v) + 1.f; stM[in] = v; }
          else stS[in] += expf(v - m);
        }
        if constexpr (SMODE == 2) { stS[in] += v; stQ[in] = fmaf(v, v, stQ[in]); }
        if constexpr (SMODE == 3) rq3 = fmaf(v, v, rq3);
        if (Cz) Cz[off] = v;
        if (C2z) C2z[off] = f2b(v);
      }
      if constexpr (SMODE == 3) {
        rq3 += __shfl_xor(rq3, 1);
        rq3 += __shfl_xor(rq3, 2);
        rq3 += __shfl_xor(rq3, 4);
        rq3 += __shfl_xor(rq3, 8);
        if (fr == 0) atomicAdd(&sp0[(ll)z * NPOS + i], rq3);
      }
    }
  }
  if constexpr (SMODE == 1) {
    const ll totj = (ll)gridDim.x * BJ;
#pragma unroll
    for (int in = 0; in < FJ; ++in) {
      float m = stM[in], s = stS[in];
#pragma unroll
      for (int d = 16; d <= 32; d <<= 1) {
        float mo = __shfl_xor(m, d);
        float so = __shfl_xor(s, d);
        float M = fmaxf(m, mo);
        s = s * expf(m - M) + so * expf(mo - M);
        m = M;
      }
      if (cl == 0) {
        ll o = ((ll)z * gridDim.y + blockIdx.y) * totj + (j0 + wj + in * 16 + fr);
        sp0[o] = m; sp1[o] = s;
      }
    }
  }
  if constexpr (SMODE == 2) {
    const ll totj = (ll)gridDim.x * BJ;
#pragma unroll
    for (int in = 0; in < FJ; ++in) {
      float s = stS[in], q = stQ[in];
      s += __shfl_xor(s, 16); s += __shfl_xor(s, 32);
      q += __shfl_xor(q, 16); q += __shfl_xor(q, 32);
      if (cl == 0) {
        ll o = ((ll)z * totj + (j0 + wj + in * 16 + fr)) * 2;
        atomicAdd(&sp0[o], s);
        atomicAdd(&sp0[o + 1], q);
      }
    }
  }
}

// ---------------- zero-init atomic targets (re-run every launch) -------
__global__ void zero_k(float* __restrict__ p, int n)
{
  int i = blockIdx.x * 1024 + threadIdx.x * 4;
  if (i < n) *(float4*)(p + i) = make_float4(0.f, 0.f, 0.f, 0.f);
}

// ---------------- init: transpose inputs [c][n] -> [n][c] ----------------
__global__ void transpose_in_k(const float* __restrict__ dq, const float* __restrict__ d3,
                               float* __restrict__ stf, short* __restrict__ stb)
{
  __shared__ float tile[64][65];
  int z = blockIdx.z;
  const float* src = (z < 2) ? dq + (ll)z * 786432 : d3 + (ll)(z - 2) * 786432;
  int c0 = blockIdx.y * 64, n0 = blockIdx.x * 64;
  int t = threadIdx.x;
  int nj = t & 63, q = t >> 6;
#pragma unroll
  for (int i = 0; i < 16; ++i) {
    int ci = q + i * 4;
    tile[ci][nj] = src[(ll)(c0 + ci) * NPOS + n0 + nj];
  }
  __syncthreads();
  int cj = t & 63;
#pragma unroll
  for (int i = 0; i < 16; ++i) {
    int ni = q + i * 4;
    float v = tile[cj][ni];
    ll o = (ll)z * 786432 + (ll)(n0 + ni) * 256 + c0 + cj;
    stf[o] = v;
    stb[o] = f2b(v);
  }
}

// ---------------- weight conversions ----------------
__global__ void f2b_k(const float* __restrict__ src, short* __restrict__ dst, int n8)
{
  int gi = blockIdx.x * 256 + threadIdx.x;
  if (gi >= n8) return;
  ll e = (ll)gi * 8;
  float4 a = *(const float4*)(src + e);
  float4 b = *(const float4*)(src + e + 4);
  uint4 o;
  o.x = pk2(a.x, a.y); o.y = pk2(a.z, a.w);
  o.z = pk2(b.x, b.y); o.w = pk2(b.z, b.w);
  *(uint4*)(dst + e) = o;
}

// mlp1w split: cols <256 -> mlp1c first half; cols >=256 -> compact m1b
__global__ void f2b_split_k(const float* __restrict__ src, short* __restrict__ d1,
                            short* __restrict__ d2)
{
  int gi = blockIdx.x * 256 + threadIdx.x;   // 262144 threads
  ll e = (ll)gi * 8;
  int k = (int)(e & 511);
  ll row = e >> 9;                            // ai*512 + o
  float4 a = *(const float4*)(src + e);
  float4 b = *(const float4*)(src + e + 4);
  uint4 o;
  o.x = pk2(a.x, a.y); o.y = pk2(a.z, a.w);
  o.z = pk2(b.x, b.y); o.w = pk2(b.z, b.w);
  if (k < 256) *(uint4*)(d1 + row * 512 + k) = o;
  else         *(uint4*)(d2 + row * 256 + (k - 256)) = o;
}

// projw rows permuted: new row sec*256 + (h*64+dh) <- old row sec*256 + (dh*4+h)
__global__ void projw_perm_k(const float* __restrict__ src, short* __restrict__ dst)
{
  int idx = blockIdx.x * 256 + threadIdx.x;   // 8*768*256
  int c = idx & 255;
  int row = (idx >> 8) % 768;
  int ai = (idx >> 8) / 768;
  int sec = row >> 8;
  int p = row & 255;
  int o = (p & 63) * 4 + (p >> 6);
  dst[idx] = f2b(src[(((ll)ai * 3 + sec) * 256 + o) * 256 + c]);
}

__global__ void pbp_k(const float* __restrict__ pb, float* __restrict__ pbp)
{
  int idx = blockIdx.x * 256 + threadIdx.x;   // 6144
  int row = idx % 768, ai = idx / 768;
  int sec = row >> 8;
  int p = row & 255;
  int o = (p & 63) * 4 + (p >> 6);
  pbp[idx] = pb[ai * 768 + (sec << 8) + o];
}

// mergewT[ai][p][c] = mergew[ai][c][cin(p)], cin(p) = (p&63)*4 + (p>>6)
__global__ void mergewT_k(const float* __restrict__ src, short* __restrict__ dst)
{
  __shared__ float tile[64][65];
  int ai = blockIdx.z;
  int p0 = blockIdx.x * 64, c0 = blockIdx.y * 64;
  int h = p0 >> 6;
  int t = threadIdx.x;
  int q = t & 63, cq = t >> 6;
#pragma unroll
  for (int i = 0; i < 16; ++i) {
    int cc = cq + i * 4;
    tile[q][cc] = src[(ll)ai * 65536 + (ll)(c0 + cc) * 256 + 4 * q + h];
  }
  __syncthreads();
#pragma unroll
  for (int i = 0; i < 16; ++i) {
    int pi = cq + i * 4;
    dst[((ll)ai * 256 + p0 + pi) * 256 + c0 + q] = f2b(tile[pi][q]);
  }
}

// folded mlp1 bias: b1c[ai][o] = mlp1b[ai][o] + sum_c mlp1w[ai][o][256+c]*mergeb[ai][c]
__global__ void biasfold_k(const float* __restrict__ mlp1w, const float* __restrict__ mlp1b,
                           const float* __restrict__ mergeb, float* __restrict__ b1c)
{
  int b = blockIdx.x;            // 64 blocks: ai = b>>3, o-group = (b&7)*64
  int ai = b >> 3, o0 = (b & 7) * 64;
  int t = threadIdx.x;
  int w = t >> 6, lane = t & 63;
  float4 mb = *(const float4*)(mergeb + ai * 256 + lane * 4);
#pragma unroll
  for (int ol = 0; ol < 16; ++ol) {
    int o = o0 + w * 16 + ol;
    float4 wv = *(const float4*)(mlp1w + ((ll)(ai * 512 + o)) * 512 + 256 + lane * 4);
    float s = wv.x * mb.x + wv.y * mb.y + wv.z * mb.z + wv.w * mb.w;
    s = waveSum(s);
    if (lane == 0) b1c[ai * 512 + o] = mlp1b[ai * 512 + o] + s;
  }
}

// gatW transposed (LDS-tiled): dst[gi][o][d] = src[gi][d][o]
__global__ void gatw_t_k(const float* __restrict__ src, short* __restrict__ dst)
{
  __shared__ float tile[64][65];
  int gi = blockIdx.z;
  int d0 = blockIdx.x * 64, o0 = blockIdx.y * 64;
  int t = threadIdx.x;
  int nj = t & 63, q = t >> 6;
#pragma unroll
  for (int i = 0; i < 16; ++i) {
    int di = q + i * 4;
    tile[di][nj] = src[(ll)gi * 65536 + (ll)(d0 + di) * 256 + o0 + nj];
  }
  __syncthreads();
#pragma unroll
  for (int i = 0; i < 16; ++i) {
    int oi = q + i * 4;
    dst[(ll)gi * 65536 + (ll)(o0 + oi) * 256 + d0 + nj] = f2b(tile[nj][oi]);
  }
}

// ---------------- GAT ----------------
__global__ void gat_prep_k(const float* __restrict__ gatW, const float* __restrict__ gata,
                           float* __restrict__ uvec)
{
  int gi = blockIdx.x; int d = threadIdx.x;
  const float* W = gatW + (ll)gi * 65536;
  const float* a = gata + gi * 512;
  float u0 = 0.f, u1 = 0.f;
  for (int o = 0; o < 256; o += 4) {
    float4 w4 = *(const float4*)(W + d * 256 + o);
    float4 a4 = *(const float4*)(a + o);
    float4 b4 = *(const float4*)(a + 256 + o);
    u0 += w4.x * a4.x + w4.y * a4.y + w4.z * a4.z + w4.w * a4.w;
    u1 += w4.x * b4.x + w4.y * b4.y + w4.z * b4.z + w4.w * b4.w;
  }
  uvec[gi * 512 + d] = u0;
  uvec[gi * 512 + 256 + d] = u1;
}

// all 4 layers' e2 in one pass over d2db. grid (96, 2)
__global__ void e2all_k(const float* __restrict__ d2db, const float* __restrict__ uvec,
                        float* __restrict__ e2all)
{
  __shared__ float us[1024];
  int t = threadIdx.x;
  for (int idx = t; idx < 1024; idx += 256)
    us[idx] = uvec[(idx >> 8) * 512 + 256 + (idx & 255)];
  __syncthreads();
  int m = blockIdx.x * 256 + t;
  int b = blockIdx.y;
  const float* xb = d2db + (ll)b * 6291456;
  float a[4] = {};
  for (int c = 0; c < 256; ++c) {
    float v = xb[(ll)c * 24576 + m];
#pragma unroll
    for (int g = 0; g < 4; ++g) a[g] = fmaf(v, us[g * 256 + c], a[g]);
  }
#pragma unroll
  for (int g = 0; g < 4; ++g) e2all[((ll)g * 2 + b) * 24576 + m] = a[g];
}

// gat attention (fused) + g accumulation:
// g[b][n][c] = at0*d3[n][c] + sum_l at[l+1]*d2db[b][c][n*8+l]
// att recomputed per block (4x redundant across c0, cheap). grid (48, 4, 2)
__global__ __launch_bounds__(256) void gat_g_k(
    const short* __restrict__ stb, const float* __restrict__ d2db,
    const float* __restrict__ uvec, const float* __restrict__ e2all,
    short* __restrict__ g, int gi)
{
  __shared__ float ush[512];
  __shared__ float attw[576];
  __shared__ float gtile[64 * 69];
  const int n0 = blockIdx.x * 64, c0 = blockIdx.y * 64, b = blockIdx.z;
  const int t = threadIdx.x;
  for (int idx = t; idx < 512; idx += 256) ush[idx] = uvec[gi * 512 + idx];
  __syncthreads();
  {
    const int q = t & 3, pl = t >> 2;
    const int n = n0 + pl;
    const short* xr = stb + (ll)(2 + b) * 786432 + (ll)n * 256 + q * 64;
    float a0 = 0.f, a1 = 0.f;
#pragma unroll
    for (int i = 0; i < 8; ++i) {
      s8v v8 = *(const s8v*)(xr + i * 8);
#pragma unroll
      for (int j = 0; j < 8; ++j) {
        float v = b2f(v8[j]);
        a0 = fmaf(v, ush[q * 64 + i * 8 + j], a0);
        a1 = fmaf(v, ush[256 + q * 64 + i * 8 + j], a1);
      }
    }
    a0 += __shfl_xor(a0, 1); a0 += __shfl_xor(a0, 2);
    a1 += __shfl_xor(a1, 1); a1 += __shfl_xor(a1, 2);
    if (q == 0) {
      float e[9];
      e[0] = a0 + a1;
      const float* e2b = e2all + ((ll)gi * 2 + b) * 24576 + (ll)n * 8;
#pragma unroll
      for (int l = 0; l < 8; ++l) e[l + 1] = a0 + e2b[l];
      float mx = -3.4e38f;
#pragma unroll
      for (int l = 0; l < 9; ++l) {
        e[l] = e[l] >= 0.f ? e[l] : 0.2f * e[l];
        mx = fmaxf(mx, e[l]);
      }
      float s = 0.f;
#pragma unroll
      for (int l = 0; l < 9; ++l) { e[l] = expf(e[l] - mx); s += e[l]; }
      float inv = 1.f / s;
#pragma unroll
      for (int l = 0; l < 9; ++l) attw[pl * 9 + l] = e[l] * inv;
    }
  }
  __syncthreads();
  const int nl = t >> 2, l2 = (t & 3) * 2;
  for (int cc = 0; cc < 64; ++cc) {
    const float* src = d2db + ((ll)b * 256 + c0 + cc) * 24576 + (ll)n0 * 8;
    float2 v = *(const float2*)(src + t * 2);
    float p = v.x * attw[nl * 9 + 1 + l2] + v.y * attw[nl * 9 + 2 + l2];
    p += __shfl_xor(p, 1);
    p += __shfl_xor(p, 2);
    if ((t & 3) == 0) gtile[nl * 69 + cc] = p;
  }
  __syncthreads();
#pragma unroll
  for (int i = 0; i < 4; ++i) {
    int n = (t >> 4) + i * 16;
    int cp = (t & 15) * 4;
    float at0 = attw[n * 9];
    const short* dr = stb + (ll)(2 + b) * 786432 + (ll)(n0 + n) * 256 + c0 + cp;
    uint2 dv = *(const uint2*)dr;
    float d0 = b2f((short)(dv.x & 0xffff)), d1 = b2f((short)(dv.x >> 16));
    float d2 = b2f((short)(dv.y & 0xffff)), d3v = b2f((short)(dv.y >> 16));
    uint2 ov;
    ov.x = pk2(gtile[n * 69 + cp] + at0 * d0, gtile[n * 69 + cp + 1] + at0 * d1);
    ov.y = pk2(gtile[n * 69 + cp + 2] + at0 * d2, gtile[n * 69 + cp + 3] + at0 * d3v);
    *(uint2*)(g + (ll)b * 786432 + (ll)(n0 + n) * 256 + c0 + cp) = ov;
  }
}

// ---------------- linear attention (h-planar channels) ----------------
// atomics directly into zero-init'd per-layer kv slot ([d][q]) + ksum
__global__ __launch_bounds__(256) void kv_partial_k(
    const short* __restrict__ qkv, float* __restrict__ kvat, float* __restrict__ ksat)
{
  __shared__ float ks[32][66];
  __shared__ float vs[32][66];
  const int p = blockIdx.x, h = blockIdx.y, z = blockIdx.z;
  const short* base = qkv + (ll)z * 2359296;
  const int t = threadIdx.x;
  const int tq = (t >> 4) * 4, tk = (t & 15) * 4;
  const int ml = t >> 3, d8 = (t & 7) * 8;
  float acc[4][4] = {};
  float ksl = 0.f;
  for (int sub = 0; sub < 8; ++sub) {
    int m0 = p * 256 + sub * 32;
    {
      const short* kr = base + (ll)(m0 + ml) * 768 + 256 + h * 64 + d8;
      s8v k8 = *(const s8v*)kr;
      s8v v8 = *(const s8v*)(kr + 256);
#pragma unroll
      for (int j = 0; j < 8; ++j) {
        float kvv = b2f(k8[j]);
        ks[ml][d8 + j] = kvv > 0.f ? kvv + 1.f : expf(kvv);  // elu+1
        vs[ml][d8 + j] = b2f(v8[j]);
      }
    }
    __syncthreads();
#pragma unroll 8
    for (int mm = 0; mm < 32; ++mm) {
      float vv[4], kk[4];
#pragma unroll
      for (int i = 0; i < 4; ++i) { vv[i] = vs[mm][tq + i]; kk[i] = ks[mm][tk + i]; }
#pragma unroll
      for (int i = 0; i < 4; ++i)
#pragma unroll
        for (int j = 0; j < 4; ++j)
          acc[i][j] = fmaf(vv[i], kk[j], acc[i][j]);
    }
    if (t < 64) {
#pragma unroll 8
      for (int mm = 0; mm < 32; ++mm) ksl += ks[mm][t];
    }
    __syncthreads();
  }
  float* kvz = kvat + ((ll)z * 4 + h) * 4096;
#pragma unroll
  for (int i = 0; i < 4; ++i)
#pragma unroll
    for (int j = 0; j < 4; ++j)
      atomicAdd(&kvz[(tk + j) * 64 + tq + i], acc[i][j]);   // [d][q]
  if (t < 64) atomicAdd(&ksat[(z * 4 + h) * 64 + t], ksl);
}

__global__ __launch_bounds__(256) void attn_out_k(
    const short* __restrict__ qkv, const float* __restrict__ kv,
    const float* __restrict__ ksum, short* __restrict__ obuf)
{
  __shared__ float qt[64][67];
  __shared__ float kvT[64][66];
  __shared__ float zsh[64];
  __shared__ float kss[64];
  const int n0 = blockIdx.x * 64, h = blockIdx.y, z = blockIdx.z;
  const int t = threadIdx.x;
  {
    int nl = t >> 3, d8 = (t & 7) * 8;
    const short* qr0 = qkv + (ll)z * 2359296 + (ll)(n0 + nl) * 768 + h * 64 + d8;
#pragma unroll
    for (int i = 0; i < 2; ++i) {
      const short* qr = qr0 + (ll)i * 32 * 768;
      s8v q8 = *(const s8v*)qr;
#pragma unroll
      for (int j = 0; j < 8; ++j) {
        float q = b2f(q8[j]);
        qt[nl + i * 32][d8 + j] = q > 0.f ? q + 1.f : expf(q);
      }
    }
  }
  {
    const float* kvb = kv + (ll)(z * 4 + h) * 4096;
#pragma unroll
    for (int i = 0; i < 16; ++i) {
      int idx = t + i * 256;
      kvT[idx >> 6][idx & 63] = kvb[idx];
    }
  }
  if (t < 64) kss[t] = ksum[(z * 4 + h) * 64 + t];
  __syncthreads();
  if (t < 64) {
    float s = 0.f;
    for (int d = 0; d < 64; ++d) s = fmaf(qt[t][d], kss[d], s);
    zsh[t] = 1.f / (s + 1e-6f);
  }
  __syncthreads();
  const int tn = t >> 4, tj = t & 15;
  float acc[4][4] = {};
  for (int d = 0; d < 64; ++d) {
    float av[4], bv[4];
#pragma unroll
    for (int i = 0; i < 4; ++i) av[i] = qt[tn * 4 + i][d];
    *(float4*)bv = *(const float4*)&kvT[d][tj * 4];
#pragma unroll
    for (int i = 0; i < 4; ++i)
#pragma unroll
      for (int j = 0; j < 4; ++j)
        acc[i][j] = fmaf(av[i], bv[j], acc[i][j]);
  }
#pragma unroll
  for (int i = 0; i < 4; ++i) {
    int n = n0 + tn * 4 + i;
    float zv = zsh[tn * 4 + i];
    uint2 o;
    o.x = pk2(acc[i][0] * zv, acc[i][1] * zv);
    o.y = pk2(acc[i][2] * zv, acc[i][3] * zv);
    *(uint2*)(obuf + (ll)z * 786432 + (ll)n * 256 + h * 64 + tj * 4) = o;
  }
}

// ---------------- instnorm apply (+relu); stats fused into mlp1 gemm ------
__global__ void in_apply_k(short* __restrict__ hid, const float* __restrict__ inat)
{
  int z = blockIdx.z, cg = blockIdx.y, nc = blockIdx.x;
  int t = threadIdx.x;
  int c = cg * 64 + (t & 63);
  float2 sq = *(const float2*)(inat + ((ll)(z * 512 + c) << 1));
  float mu = sq.x * (1.f / NPOS);
  float var = sq.y * (1.f / NPOS) - mu * mu;
  float rsig = rsqrtf(fmaxf(var, 0.f) + 1e-5f);
  short* base = hid + (ll)z * 1572864 + (ll)(nc * 384 + (t >> 6)) * 512 + c;
#pragma unroll 4
  for (int i = 0; i < 96; ++i) {
    float v = (b2f(base[(ll)i * 2048]) - mu) * rsig;
    base[(ll)i * 2048] = f2b(v > 0.f ? v : 0.f);
  }
}

// ---------------- final epilogue ----------------
__global__ void colstat_comb_k(const float* __restrict__ pmax, const float* __restrict__ psum,
                               float* __restrict__ cmax, float* __restrict__ csum)
{
  int m = blockIdx.x * 256 + threadIdx.x; int b = blockIdx.y;
  float M = -3.4e38f;
  for (int c = 0; c < 48; ++c) M = fmaxf(M, pmax[((ll)b * 48 + c) * NPOS + m]);
  float s = 0.f;
  for (int c = 0; c < 48; ++c)
    s += psum[((ll)b * 48 + c) * NPOS + m] * expf(pmax[((ll)b * 48 + c) * NPOS + m] - M);
  cmax[b * NPOS + m] = M; csum[b * NPOS + m] = s;
}

__global__ __launch_bounds__(256) void rowfix_k(
    float* __restrict__ S, const float* __restrict__ cmax, const float* __restrict__ csum,
    int* __restrict__ i0, float* __restrict__ m0)
{
  int n = blockIdx.x, b = blockIdx.y, t = threadIdx.x;
  float* row = S + (ll)b * 9437184 + (ll)n * NPOS;
  __shared__ float red[4];
  float v[12];
  float mx = -3.4e38f;
#pragma unroll
  for (int i = 0; i < 12; ++i) { v[i] = row[t + i * 256]; mx = fmaxf(mx, v[i]); }
#pragma unroll
  for (int off = 32; off > 0; off >>= 1) mx = fmaxf(mx, __shfl_down(mx, off));
  if ((t & 63) == 0) red[t >> 6] = mx;
  __syncthreads();
  float rm = fmaxf(fmaxf(red[0], red[1]), fmaxf(red[2], red[3]));
  __syncthreads();
  float s = 0.f;
#pragma unroll
  for (int i = 0; i < 12; ++i) s += expf(v[i] - rm);
  s = waveSum(s);
  if ((t & 63) == 0) red[t >> 6] = s;
  __syncthreads();
  float irs = 1.f / (red[0] + red[1] + red[2] + red[3]);
  float bv = -1.f; int bi = 0;
#pragma unroll
  for (int i = 0; i < 12; ++i) {
    int m = t + i * 256;
    float f = expf(2.f * v[i] - rm - cmax[b * NPOS + m]) * irs / csum[b * NPOS + m];
    row[m] = f;
    if (f > bv) { bv = f; bi = m; }
  }
  if (b == 0) {
#pragma unroll
    for (int off = 32; off > 0; off >>= 1) {
      float ov = __shfl_down(bv, off);
      int oi = __shfl_down(bi, off);
      if (ov > bv || (ov == bv && oi < bi)) { bv = ov; bi = oi; }
    }
    __shared__ float rv[4]; __shared__ int ri[4];
    if ((t & 63) == 0) { rv[t >> 6] = bv; ri[t >> 6] = bi; }
    __syncthreads();
    if (t == 0) {
      for (int w = 1; w < 4; ++w)
        if (rv[w] > bv || (rv[w] == bv && ri[w] < bi)) { bv = rv[w]; bi = ri[w]; }
      i0[n] = bi; m0[n] = bv;
    }
  }
}

__global__ void colamax_part_k(const float* __restrict__ Cf,
                               float* __restrict__ capv, int* __restrict__ capi)
{
  int m = blockIdx.x * 256 + threadIdx.x;
  int n0 = blockIdx.y * 128;
  float bv = -1.f; int bi = 0;
  for (int n = n0; n < n0 + 128; ++n) {
    float f = Cf[(ll)n * NPOS + m];
    if (f > bv) { bv = f; bi = n; }
  }
  capv[blockIdx.y * NPOS + m] = bv;
  capi[blockIdx.y * NPOS + m] = bi;
}

__global__ void colamax_comb_k(const float* __restrict__ capv, const int* __restrict__ capi,
                               int* __restrict__ i1)
{
  int m = blockIdx.x * 256 + threadIdx.x;
  float bv = -1.f; int bi = 0;
  for (int c = 0; c < 24; ++c) {
    float v = capv[c * NPOS + m];
    if (v > bv) { bv = v; bi = capi[c * NPOS + m]; }
  }
  i1[m] = bi;
}

__global__ void match0_k(const int* __restrict__ i0, const float* __restrict__ m0,
                         const int* __restrict__ i1, float* __restrict__ out)
{
  int n = blockIdx.x * 256 + threadIdx.x;
  int j = i0[n];
  bool mut = (i1[j] == n);
  float ms0 = mut ? m0[n] : 0.f;
  bool valid = mut && (ms0 > 0.2f);
  out[n] = valid ? (float)j : -1.f;
  out[6144 + n] = ms0;
}

__global__ void match1_k(const int* __restrict__ i0, const int* __restrict__ i1,
                         float* __restrict__ out)
{
  int m = blockIdx.x * 256 + threadIdx.x;
  int j = i1[m];
  bool mut = (i0[j] == m);
  float ms0v = out[6144 + j];
  float ind0v = out[j];
  float ms1 = mut ? ms0v : 0.f;
  bool valid1 = mut && (ind0v >= 0.f);
  out[3072 + m] = valid1 ? (float)j : -1.f;
  out[9216 + m] = ms1;
}

// ------------------------------------------------------------------
extern "C" void kernel_launch(void* const* d_in, const int* in_sizes, int n_in,
                              void* d_out, int out_size, void* d_ws, size_t ws_size,
                              hipStream_t stream)
{
  const float* desc2dq = (const float*)d_in[0];
  const float* desc3db = (const float*)d_in[1];
  const float* desc2db = (const float*)d_in[2];
  const float* projw = (const float*)d_in[3];
  const float* projb = (const float*)d_in[4];
  const float* mergew = (const float*)d_in[5];
  const float* mergeb = (const float*)d_in[6];
  const float* mlp1w = (const float*)d_in[7];
  const float* mlp1b = (const float*)d_in[8];
  const float* mlp2w = (const float*)d_in[9];
  const float* mlp2b = (const float*)d_in[10];
  const float* gatW = (const float*)d_in[11];
  const float* gata = (const float*)d_in[12];
  const float* finw = (const float*)d_in[13];
  const float* finb = (const float*)d_in[14];

  float* ws = (float*)d_ws;
  float* out = (float*)d_out;

  float* stf = ws + OFF_STF;
  short* stb = (short*)(ws + OFF_STB);
  short* qkv = (short*)(ws + OFF_QKV);
  short* msg = (short*)(ws + OFF_MSG);
  short* obuf = msg;
  short* hid = (short*)(ws + OFF_HID);
  short* wbf = (short*)(ws + OFF_WBF);
  short* projw_bf = wbf;
  short* mergewT_bf = wbf + 1572864;
  short* mlp1c_bf = wbf + 2097152;
  short* mlp2w_bf = wbf + 4194304;
  short* gatwT_bf = wbf + 5242880;
  short* finw_bf = wbf + 5505024;
  float* pbp = ws + OFF_PBP;
  float* uvec = ws + OFF_UVEC;
  float* e2all = ws + OFF_E2ALL;
  float* pmax = ws + OFF_PMAX;
  float* psum = ws + OFF_PSUM;
  float* cmax = ws + OFF_CMAX;
  float* csum = ws + OFF_CSUM;
  float* capv = ws + OFF_CAPV;
  int* capi = (int*)(ws + OFF_CAPI);
  int* i0 = (int*)(ws + OFF_I0);
  float* m0 = ws + OFF_M0;
  int* i1 = (int*)(ws + OFF_I1);
  short* m1b_bf = (short*)(ws + OFF_M1B);
  float* b1c = ws + OFF_B1C;
  float* inat = ws + OFF_INAT;
  float* svsq = ws + OFF_SVSQ;
  float* kvat = ws + OFF_KVAT;
  float* ksat = ws + OFF_KSAT;
  short* finbf = msg;                      // alias (obuf dead by then)

  // ---- init ----
  zero_k<<<564, 256, 0, stream>>>(inat, (int)ZERO_N);
  transpose_in_k<<<dim3(48, 4, 4), 256, 0, stream>>>(desc2dq, desc3db, stf, stb);
  projw_perm_k<<<6144, 256, 0, stream>>>(projw, projw_bf);
  pbp_k<<<24, 256, 0, stream>>>(projb, pbp);
  mergewT_k<<<dim3(4, 4, 8), 256, 0, stream>>>(mergew, mergewT_bf);
  f2b_split_k<<<1024, 256, 0, stream>>>(mlp1w, mlp1c_bf, m1b_bf);
  f2b_k<<<512, 256, 0, stream>>>(mlp2w, mlp2w_bf, 131072);
  gatw_t_k<<<dim3(4, 4, 4), 256, 0, stream>>>(gatW, gatwT_bf);
  f2b_k<<<32, 256, 0, stream>>>(finw, finw_bf, 8192);
  biasfold_k<<<64, 256, 0, stream>>>(mlp1w, mlp1b, mergeb, b1c);
  // M2[ai][o][p] = sum_c mlp1w[ai][o][256+c] * mergew[ai][c][cin(p)]
  bgemm_k<64, 128, 256, 0><<<dim3(2, 8, 8), 256, 0, stream>>>(
      m1b_bf, nullptr, 0, 256, 0, mergewT_bf, nullptr, nullptr,
      nullptr, mlp1c_bf + 256, nullptr, nullptr,
      512, 1.f, 131072, 0, 65536, 0, 0, 262144, 0, 0, 0, 7, 0, 0,
      nullptr, nullptr, 0);
  gat_prep_k<<<4, 256, 0, stream>>>(gatW, gata, uvec);
  e2all_k<<<dim3(96, 2), 256, 0, stream>>>(desc2db, uvec, e2all);

  auto attn_layer = [&](int ai, int cross) {
    const short* pw = projw_bf + (ll)ai * 196608;
    const float* pb = pbp + (ll)ai * 768;
    // qkv projection: one dispatch; for cross, blocks with bx<2 (q cols)
    // read the dq state (zaq=0) while k/v cols read the src state (za=2)
    bgemm_k<64, 128, 256, 0><<<dim3(6, 48, 4), 256, 0, stream>>>(
        stb, nullptr, 0, 256, 0, pw, pb, nullptr, nullptr, qkv, nullptr, nullptr,
        768, 1.f, 786432, 0, 0, 0, 0, 2359296, cross ? 2 : 0, 0, 0, 3,
        cross ? 2 : 0, 0,
        nullptr, nullptr, 0);
    kv_partial_k<<<dim3(12, 4, 4), 256, 0, stream>>>(
        qkv, kvat + (ll)ai * 65536, ksat + (ll)ai * 1024);
    attn_out_k<<<dim3(48, 4, 4), 256, 0, stream>>>(
        qkv, kvat + (ll)ai * 65536, ksat + (ll)ai * 1024, obuf);
    // merge folded into mlp1: hid = stb@W1a + obuf@M2 + b1c; instnorm stats fused
    bgemm_k<64, 128, 512, 2><<<dim3(4, 48, 4), 256, 0, stream>>>(
        stb, obuf, 256, 256, 256, mlp1c_bf + (ll)ai * 262144, b1c + (ll)ai * 512,
        nullptr, nullptr, hid, nullptr, nullptr,
        512, 1.f, 786432, 786432, 0, 0, 0, 1572864, 0, 0, 0, 3, 0, 0,
        inat + (ll)ai * 4096, nullptr, 0);
    in_apply_k<<<dim3(8, 8, 4), 256, 0, stream>>>(hid, inat + (ll)ai * 4096);
    bgemm_k<64, 64, 512, 0><<<dim3(4, 48, 4), 256, 0, stream>>>(
        hid, nullptr, 0, 512, 0, mlp2w_bf + (ll)ai * 131072, mlp2b + (ll)ai * 256,
        stf, stf, stb, nullptr, nullptr,
        256, 1.f, 1572864, 0, 0, 786432, 786432, 786432, 0, 0, 0, 3, 0, 0,
        nullptr, nullptr, 0);
  };

  auto gat_layer = [&](int gi) {
    gat_g_k<<<dim3(48, 4, 2), 256, 0, stream>>>(stb, desc2db, uvec, e2all, obuf, gi);
    bgemm_k<64, 64, 256, 0><<<dim3(4, 48, 2), 256, 0, stream>>>(
        obuf, nullptr, 0, 256, 0, gatwT_bf + (ll)gi * 65536, nullptr, nullptr,
        stf + (ll)2 * 786432, stb + (ll)2 * 786432, nullptr, nullptr,
        256, 1.f, 786432, 0, 0, 0, 786432, 786432, 0, 0, 1, 3, 0, 0,
        nullptr, nullptr, 0);
  };

  int ai = 0, gi = 0;
  for (int r = 0; r < 4; ++r) {
    gat_layer(gi); gi++;
    attn_layer(ai, 0); ai++;   // self
    attn_layer(ai, 1); ai++;   // cross
  }

  // final projection -> bf16; row sumsq fused (svsq)
  bgemm_k<64, 64, 256, 3><<<dim3(4, 48, 4), 256, 0, stream>>>(
      stb, nullptr, 0, 256, 0, finw_bf, finb, nullptr, nullptr, finbf, nullptr, nullptr,
      256, 1.f, 786432, 0, 0, 0, 0, 786432, 0, 0, 0, 3, 0, 0,
      svsq, nullptr, 0);

  // scores = 10 * norm(mq)[n] . norm(md)[m]; col softmax stats fused (pmax/psum)
  float* conf = out + 12288;
  bgemm_k<64, 128, 256, 1><<<dim3(24, 48, 2), 256, 0, stream>>>(
      finbf, nullptr, 0, 256, 0, finbf, nullptr, nullptr, conf, nullptr, svsq, svsq,
      3072, 10.f, 786432, 0, 786432, 0, 9437184, 0, 0, 2, 0, 3, 0, 0,
      pmax, psum, 1);

  colstat_comb_k<<<dim3(12, 2), 256, 0, stream>>>(pmax, psum, cmax, csum);
  rowfix_k<<<dim3(NPOS, 2), 256, 0, stream>>>(conf, cmax, csum, i0, m0);
  colamax_part_k<<<dim3(12, 24), 256, 0, stream>>>(conf, capv, capi);
  colamax_comb_k<<<12, 256, 0, stream>>>(capv, capi, i1);
  match0_k<<<12, 256, 0, stream>>>(i0, m0, i1, out);
  match1_k<<<12, 256, 0, stream>>>(i0, i1, out);
}

// Round 8
// 1476.867 us; speedup vs baseline: 1.0534x; 1.0534x over previous
//
#include <hip/hip_runtime.h>
#include <hip/hip_bf16.h>
#include <math.h>

typedef long long ll;
typedef __attribute__((ext_vector_type(8))) short s8v;
typedef __attribute__((ext_vector_type(4))) float f4v;
typedef __attribute__((address_space(1))) unsigned int gu32;
typedef __attribute__((address_space(3))) unsigned int lu32;

#define NPOS 3072
// state z layout: [0]=dq_b0 [1]=dq_b1 [2]=d3_b0 [3]=d3_b1
// ALL activations position-major: [z][n][c]

// ---------------- workspace offsets (floats) ----------------
#define OFF_STF   0LL          /* fp32 state [4][3072][256] */
#define OFF_STB   3145728LL    /* bf16 state (shorts) */
#define OFF_QKV   4718592LL    /* bf16 [4][3072][768] shorts */
#define OFF_MSG   9437184LL    /* bf16 [4][3072][256] shorts; obuf + finbf alias */
#define OFF_HID   11010048LL   /* bf16 [4][3072][512] shorts */
#define OFF_WBF   14155776LL   /* bf16 weights, 5,570,560 shorts */
#define OFF_PBP   16941056LL   /* permuted projb fp32 [8][768] */
#define OFF_UVEC  17026048LL
#define OFF_E2ALL 17028096LL   /* [4][2][24576] */
#define OFF_PMAX  17300480LL
#define OFF_PSUM  17595392LL
#define OFF_CMAX  17890304LL
#define OFF_CSUM  17896448LL
#define OFF_CAPV  17902592LL
#define OFF_CAPI  17976320LL
#define OFF_I0    18050048LL
#define OFF_M0    18053120LL
#define OFF_I1    18056192LL
#define OFF_M1B   18059264LL   /* bf16 [8][512][256] shorts (mlp1w second half) */
#define OFF_B1C   18583552LL   /* fp32 [8][512] folded mlp1 bias */
#define OFF_INAT  18587648LL   /* fp32 [8][4][512][2] instnorm atomic sums */
#define OFF_SVSQ  18620416LL   /* fp32 [4][3072] fin row sumsq */
#define OFF_KVAT  18632704LL   /* fp32 [8][16][4096] kv atomic */
#define OFF_KSAT  19156992LL   /* fp32 [8][16][64] ksum atomic */
#define ZERO_N    577536LL     /* floats from OFF_INAT to end of KSAT */

__device__ __forceinline__ float b2f(short s) {
  union { unsigned u; float f; } c;
  c.u = ((unsigned)(unsigned short)s) << 16;
  return c.f;
}
__device__ __forceinline__ short f2b(float f) {
  __hip_bfloat16 h = __float2bfloat16(f);
  union { __hip_bfloat16 h; short s; } c; c.h = h; return c.s;
}
__device__ __forceinline__ unsigned pk2(float a, float b) {
  return (unsigned)(unsigned short)f2b(a) | ((unsigned)(unsigned short)f2b(b) << 16);
}
__device__ __forceinline__ float waveSum(float v) {
#pragma unroll
  for (int off = 32; off > 0; off >>= 1) v += __shfl_down(v, off);
  return v;
}
// async 16B global->LDS DMA (dest must be wave-uniform base + lane*16, linear)
__device__ __forceinline__ void gld16(const short* g, short* l) {
  __builtin_amdgcn_global_load_lds((const gu32*)g, (lu32*)l, 16, 0, 0);
}
template<int N> __device__ __forceinline__ void wvm() {
  asm volatile("s_waitcnt vmcnt(%0)" :: "n"(N) : "memory");
}
__device__ __forceinline__ void wlgk0() {
  asm volatile("s_waitcnt lgkmcnt(0)" ::: "memory");
}

// ------------------------------------------------------------------
// bf16 MFMA GEMM, position-major: C[i][j] = act(alpha*sum_k A[i][k]B[j][k]
//   (*rs[i]*cs[j]) + bias[j] + R[i][j])
// TWO LDS buffers (24.6 KB at <64,128> -> 6 blocks/CU vs 4 with 3 bufs;
// occupancy is the isolated lever this round). Counted vmcnt: prologue
// stages tiles 0,1; iter kt = { wvm<LPT> (tile kt landed, kt+1 in
// flight), barrier, reads+MFMA, wlgk0+barrier, stage(kt+2 -> buf kt&1) }.
// Ledger: outstanding before wait = tiles {kt,kt+1} in issue order, so
// wvm<LPT> retires exactly tile kt; overwrite of buf kt&1 happens after
// all waves drained reads (wlgk0+barrier).
// XOR chunk swizzle on global source; same XOR on read -> 2-way (free).
// jq/zaq: blocks with blockIdx.x < jq use za=zaq (merged cross-attn qkv).
// SMODE epilogue stat fusion:
//   1: per-column online (max, sumexp) -> sp0/sp1[(z*gridY+by)*TOTJ + j]
//   2: per-column (sum, sumsq) -> atomicAdd sp0[(z*TOTJ + j)*2 + {0,1}]
//   3: per-row sumsq -> atomicAdd sp0[z*NPOS + i]
// rsmode=1: rs/cs hold sumsq; apply 1/max(sqrt(s),1e-12).
// ------------------------------------------------------------------
template<int BI, int BJ, int KT, int SMODE>
__global__ __launch_bounds__(256) void bgemm_k(
    const short* __restrict__ A, const short* __restrict__ A2, int KS,
    int lda, int lda2,
    const short* __restrict__ B,
    const float* __restrict__ bias, const float* __restrict__ R,
    float* __restrict__ C, short* __restrict__ C2,
    const float* __restrict__ rs, const float* __restrict__ cs,
    int ldc, float alpha,
    ll aB, ll a2B, ll bB, ll rB, ll cB, ll c2B,
    int za, int zbo, int act, int zand, int jq, int zaq,
    float* __restrict__ sp0, float* __restrict__ sp1, int rsmode)
{
  constexpr int NT = KT / 32;
  constexpr int WI = (BI == 128) ? 2 : 1;
  constexpr int JW = BJ / (4 / WI);
  constexpr int FI = (BI / WI) / 16;
  constexpr int FJ = JW / 16;
  constexpr int SA = BI / 64, SB = BJ / 64;
  constexpr int LPT = SA + SB;
  __shared__ __align__(16) short As[2][BI * 32];
  __shared__ __align__(16) short Bs[2][BJ * 32];
  const int z = blockIdx.z;
  const int zae = (jq > 0 && (int)blockIdx.x < jq) ? zaq : za;
  const int zA = (z + zae) & zand, zB = (z + zbo) & zand;
  const int j0 = blockIdx.x * BJ, i0 = blockIdx.y * BI;
  const int t = threadIdx.x;
  const int lane = t & 63, w = t >> 6;
  const int wi = (WI == 2) ? (w & 1) * 64 : 0;
  const int wj = (WI == 2) ? (w >> 1) * JW : w * JW;
  const int fr = lane & 15;
  const int cl = lane >> 4;
  const int r4 = cl * 4;

  const short* baseA[SA]; const short* baseA2[SA]; const short* baseB[SB];
  int slA[SA], slB[SB];
  {
    const short* Az = A + (ll)zA * aB;
    const short* A2z = A2 ? A2 + (ll)zA * a2B : nullptr;
    const short* Bz = B + (ll)zB * bB;
#pragma unroll
    for (int i = 0; i < SA; ++i) {
      int cc = t + i * 256;
      int r = cc >> 2;
      int sq = ((cc & 3) ^ ((r >> 1) & 3)) << 3;
      baseA[i] = Az + (ll)(i0 + r) * lda + sq;
      baseA2[i] = A2 ? A2z + (ll)(i0 + r) * lda2 + sq : nullptr;
      slA[i] = cc << 3;
    }
#pragma unroll
    for (int i = 0; i < SB; ++i) {
      int cc = t + i * 256;
      int r = cc >> 2;
      int sq = ((cc & 3) ^ ((r >> 1) & 3)) << 3;
      baseB[i] = Bz + (ll)(j0 + r) * KT + sq;
      slB[i] = cc << 3;
    }
  }
  int offA[FI], offB[FJ];
#pragma unroll
  for (int im = 0; im < FI; ++im) {
    int ra = wi + im * 16 + fr;
    offA[im] = ra * 32 + ((cl ^ ((ra >> 1) & 3)) << 3);
  }
#pragma unroll
  for (int in = 0; in < FJ; ++in) {
    int rb = wj + in * 16 + fr;
    offB[in] = rb * 32 + ((cl ^ ((rb >> 1) & 3)) << 3);
  }

  f4v acc[FI][FJ];
#pragma unroll
  for (int i = 0; i < FI; ++i)
#pragma unroll
    for (int j = 0; j < FJ; ++j) acc[i][j] = (f4v)0.f;

  auto stage = [&](int tile, int bi_) {
    const int k0 = tile * 32;
    short* dA = As[bi_]; short* dB = Bs[bi_];
    if (A2 && k0 >= KS) {
#pragma unroll
      for (int i = 0; i < SA; ++i) gld16(baseA2[i] + (k0 - KS), dA + slA[i]);
    } else {
#pragma unroll
      for (int i = 0; i < SA; ++i) gld16(baseA[i] + k0, dA + slA[i]);
    }
#pragma unroll
    for (int i = 0; i < SB; ++i) gld16(baseB[i] + k0, dB + slB[i]);
  };

  stage(0, 0);
  stage(1, 1);
#pragma unroll
  for (int kt = 0; kt < NT; ++kt) {
    if (kt + 1 < NT) { wvm<LPT>(); } else { wvm<0>(); }
    __builtin_amdgcn_s_barrier();
    asm volatile("" ::: "memory");
    const short* Ac = As[kt & 1]; const short* Bc = Bs[kt & 1];
    s8v af[FI], bfr[FJ];
#pragma unroll
    for (int im = 0; im < FI; ++im) af[im] = *(const s8v*)(Ac + offA[im]);
#pragma unroll
    for (int in = 0; in < FJ; ++in) bfr[in] = *(const s8v*)(Bc + offB[in]);
#pragma unroll
    for (int im = 0; im < FI; ++im)
#pragma unroll
      for (int in = 0; in < FJ; ++in)
        acc[im][in] = __builtin_amdgcn_mfma_f32_16x16x32_bf16(
            af[im], bfr[in], acc[im][in], 0, 0, 0);
    if (kt + 2 < NT) {
      wlgk0();                        // all reads of buf kt&1 drained
      __builtin_amdgcn_s_barrier();   // across the block
      stage(kt + 2, kt & 1);          // then overwrite it
    }
  }

  // epilogue
  float* Cz = C ? C + (ll)z * cB : nullptr;
  short* C2z = C2 ? C2 + (ll)z * c2B : nullptr;
  const float* Rz = R ? R + (ll)z * rB : nullptr;
  const float* rsz = rs ? rs + (ll)z * NPOS : nullptr;
  float bv4[FJ], cv4[FJ];
#pragma unroll
  for (int in = 0; in < FJ; ++in) {
    int j = j0 + wj + in * 16 + fr;
    bv4[in] = bias ? bias[j] : 0.f;
    cv4[in] = cs ? cs[(ll)zB * NPOS + j] : 1.f;
    if (rsmode) cv4[in] = 1.f / fmaxf(sqrtf(cv4[in]), 1e-12f);
  }
  float stM[FJ], stS[FJ], stQ[FJ];
#pragma unroll
  for (int in = 0; in < FJ; ++in) { stM[in] = -3.4e38f; stS[in] = 0.f; stQ[in] = 0.f; }

#pragma unroll
  for (int im = 0; im < FI; ++im) {
#pragma unroll
    for (int r = 0; r < 4; ++r) {
      int i = i0 + wi + im * 16 + r4 + r;
      float rsv = rsz ? rsz[i] : 1.f;
      if (rsmode) rsv = 1.f / fmaxf(sqrtf(rsv), 1e-12f);
      int rowo = i * ldc;
      float rq3 = 0.f;
#pragma unroll
      for (int in = 0; in < FJ; ++in) {
        int j = j0 + wj + in * 16 + fr;
        float v = acc[im][in][r] * alpha;
        if (rsz) v = v * rsv * cv4[in];
        v += bv4[in];
        int off = rowo + j;
        if (Rz) v += Rz[off];
        if (act) v = v > 0.f ? v : (expf(v) - 1.f);
        if constexpr (SMODE == 1) {
          float m = stM[in];
          if (v > m) { stS[in] = stS[in] * expf(m - v) + 1.f; stM[in] = v; }
          else stS[in] += expf(v - m);
        }
        if constexpr (SMODE == 2) { stS[in] += v; stQ[in] = fmaf(v, v, stQ[in]); }
        if constexpr (SMODE == 3) rq3 = fmaf(v, v, rq3);
        if (Cz) Cz[off] = v;
        if (C2z) C2z[off] = f2b(v);
      }
      if constexpr (SMODE == 3) {
        rq3 += __shfl_xor(rq3, 1);
        rq3 += __shfl_xor(rq3, 2);
        rq3 += __shfl_xor(rq3, 4);
        rq3 += __shfl_xor(rq3, 8);
        if (fr == 0) atomicAdd(&sp0[(ll)z * NPOS + i], rq3);
      }
    }
  }
  if constexpr (SMODE == 1) {
    const ll totj = (ll)gridDim.x * BJ;
#pragma unroll
    for (int in = 0; in < FJ; ++in) {
      float m = stM[in], s = stS[in];
#pragma unroll
      for (int d = 16; d <= 32; d <<= 1) {
        float mo = __shfl_xor(m, d);
        float so = __shfl_xor(s, d);
        float M = fmaxf(m, mo);
        s = s * expf(m - M) + so * expf(mo - M);
        m = M;
      }
      if (cl == 0) {
        ll o = ((ll)z * gridDim.y + blockIdx.y) * totj + (j0 + wj + in * 16 + fr);
        sp0[o] = m; sp1[o] = s;
      }
    }
  }
  if constexpr (SMODE == 2) {
    const ll totj = (ll)gridDim.x * BJ;
#pragma unroll
    for (int in = 0; in < FJ; ++in) {
      float s = stS[in], q = stQ[in];
      s += __shfl_xor(s, 16); s += __shfl_xor(s, 32);
      q += __shfl_xor(q, 16); q += __shfl_xor(q, 32);
      if (cl == 0) {
        ll o = ((ll)z * totj + (j0 + wj + in * 16 + fr)) * 2;
        atomicAdd(&sp0[o], s);
        atomicAdd(&sp0[o + 1], q);
      }
    }
  }
}

// ---------------- zero-init atomic targets (re-run every launch) -------
__global__ void zero_k(float* __restrict__ p, int n)
{
  int i = blockIdx.x * 1024 + threadIdx.x * 4;
  if (i < n) *(float4*)(p + i) = make_float4(0.f, 0.f, 0.f, 0.f);
}

// ---------------- init: transpose inputs [c][n] -> [n][c] ----------------
__global__ void transpose_in_k(const float* __restrict__ dq, const float* __restrict__ d3,
                               float* __restrict__ stf, short* __restrict__ stb)
{
  __shared__ float tile[64][65];
  int z = blockIdx.z;
  const float* src = (z < 2) ? dq + (ll)z * 786432 : d3 + (ll)(z - 2) * 786432;
  int c0 = blockIdx.y * 64, n0 = blockIdx.x * 64;
  int t = threadIdx.x;
  int nj = t & 63, q = t >> 6;
#pragma unroll
  for (int i = 0; i < 16; ++i) {
    int ci = q + i * 4;
    tile[ci][nj] = src[(ll)(c0 + ci) * NPOS + n0 + nj];
  }
  __syncthreads();
  int cj = t & 63;
#pragma unroll
  for (int i = 0; i < 16; ++i) {
    int ni = q + i * 4;
    float v = tile[cj][ni];
    ll o = (ll)z * 786432 + (ll)(n0 + ni) * 256 + c0 + cj;
    stf[o] = v;
    stb[o] = f2b(v);
  }
}

// ---------------- weight conversions ----------------
__global__ void f2b_k(const float* __restrict__ src, short* __restrict__ dst, int n8)
{
  int gi = blockIdx.x * 256 + threadIdx.x;
  if (gi >= n8) return;
  ll e = (ll)gi * 8;
  float4 a = *(const float4*)(src + e);
  float4 b = *(const float4*)(src + e + 4);
  uint4 o;
  o.x = pk2(a.x, a.y); o.y = pk2(a.z, a.w);
  o.z = pk2(b.x, b.y); o.w = pk2(b.z, b.w);
  *(uint4*)(dst + e) = o;
}

// mlp1w split: cols <256 -> mlp1c first half; cols >=256 -> compact m1b
__global__ void f2b_split_k(const float* __restrict__ src, short* __restrict__ d1,
                            short* __restrict__ d2)
{
  int gi = blockIdx.x * 256 + threadIdx.x;   // 262144 threads
  ll e = (ll)gi * 8;
  int k = (int)(e & 511);
  ll row = e >> 9;                            // ai*512 + o
  float4 a = *(const float4*)(src + e);
  float4 b = *(const float4*)(src + e + 4);
  uint4 o;
  o.x = pk2(a.x, a.y); o.y = pk2(a.z, a.w);
  o.z = pk2(b.x, b.y); o.w = pk2(b.z, b.w);
  if (k < 256) *(uint4*)(d1 + row * 512 + k) = o;
  else         *(uint4*)(d2 + row * 256 + (k - 256)) = o;
}

// projw rows permuted: new row sec*256 + (h*64+dh) <- old row sec*256 + (dh*4+h)
__global__ void projw_perm_k(const float* __restrict__ src, short* __restrict__ dst)
{
  int idx = blockIdx.x * 256 + threadIdx.x;   // 8*768*256
  int c = idx & 255;
  int row = (idx >> 8) % 768;
  int ai = (idx >> 8) / 768;
  int sec = row >> 8;
  int p = row & 255;
  int o = (p & 63) * 4 + (p >> 6);
  dst[idx] = f2b(src[(((ll)ai * 3 + sec) * 256 + o) * 256 + c]);
}

__global__ void pbp_k(const float* __restrict__ pb, float* __restrict__ pbp)
{
  int idx = blockIdx.x * 256 + threadIdx.x;   // 6144
  int row = idx % 768, ai = idx / 768;
  int sec = row >> 8;
  int p = row & 255;
  int o = (p & 63) * 4 + (p >> 6);
  pbp[idx] = pb[ai * 768 + (sec << 8) + o];
}

// mergewT[ai][p][c] = mergew[ai][c][cin(p)], cin(p) = (p&63)*4 + (p>>6)
__global__ void mergewT_k(const float* __restrict__ src, short* __restrict__ dst)
{
  __shared__ float tile[64][65];
  int ai = blockIdx.z;
  int p0 = blockIdx.x * 64, c0 = blockIdx.y * 64;
  int h = p0 >> 6;
  int t = threadIdx.x;
  int q = t & 63, cq = t >> 6;
#pragma unroll
  for (int i = 0; i < 16; ++i) {
    int cc = cq + i * 4;
    tile[q][cc] = src[(ll)ai * 65536 + (ll)(c0 + cc) * 256 + 4 * q + h];
  }
  __syncthreads();
#pragma unroll
  for (int i = 0; i < 16; ++i) {
    int pi = cq + i * 4;
    dst[((ll)ai * 256 + p0 + pi) * 256 + c0 + q] = f2b(tile[pi][q]);
  }
}

// folded mlp1 bias: b1c[ai][o] = mlp1b[ai][o] + sum_c mlp1w[ai][o][256+c]*mergeb[ai][c]
__global__ void biasfold_k(const float* __restrict__ mlp1w, const float* __restrict__ mlp1b,
                           const float* __restrict__ mergeb, float* __restrict__ b1c)
{
  int b = blockIdx.x;            // 64 blocks: ai = b>>3, o-group = (b&7)*64
  int ai = b >> 3, o0 = (b & 7) * 64;
  int t = threadIdx.x;
  int w = t >> 6, lane = t & 63;
  float4 mb = *(const float4*)(mergeb + ai * 256 + lane * 4);
#pragma unroll
  for (int ol = 0; ol < 16; ++ol) {
    int o = o0 + w * 16 + ol;
    float4 wv = *(const float4*)(mlp1w + ((ll)(ai * 512 + o)) * 512 + 256 + lane * 4);
    float s = wv.x * mb.x + wv.y * mb.y + wv.z * mb.z + wv.w * mb.w;
    s = waveSum(s);
    if (lane == 0) b1c[ai * 512 + o] = mlp1b[ai * 512 + o] + s;
  }
}

// gatW transposed (LDS-tiled): dst[gi][o][d] = src[gi][d][o]
__global__ void gatw_t_k(const float* __restrict__ src, short* __restrict__ dst)
{
  __shared__ float tile[64][65];
  int gi = blockIdx.z;
  int d0 = blockIdx.x * 64, o0 = blockIdx.y * 64;
  int t = threadIdx.x;
  int nj = t & 63, q = t >> 6;
#pragma unroll
  for (int i = 0; i < 16; ++i) {
    int di = q + i * 4;
    tile[di][nj] = src[(ll)gi * 65536 + (ll)(d0 + di) * 256 + o0 + nj];
  }
  __syncthreads();
#pragma unroll
  for (int i = 0; i < 16; ++i) {
    int oi = q + i * 4;
    dst[(ll)gi * 65536 + (ll)(o0 + oi) * 256 + d0 + nj] = f2b(tile[nj][oi]);
  }
}

// ---------------- GAT ----------------
__global__ void gat_prep_k(const float* __restrict__ gatW, const float* __restrict__ gata,
                           float* __restrict__ uvec)
{
  int gi = blockIdx.x; int d = threadIdx.x;
  const float* W = gatW + (ll)gi * 65536;
  const float* a = gata + gi * 512;
  float u0 = 0.f, u1 = 0.f;
  for (int o = 0; o < 256; o += 4) {
    float4 w4 = *(const float4*)(W + d * 256 + o);
    float4 a4 = *(const float4*)(a + o);
    float4 b4 = *(const float4*)(a + 256 + o);
    u0 += w4.x * a4.x + w4.y * a4.y + w4.z * a4.z + w4.w * a4.w;
    u1 += w4.x * b4.x + w4.y * b4.y + w4.z * b4.z + w4.w * b4.w;
  }
  uvec[gi * 512 + d] = u0;
  uvec[gi * 512 + 256 + d] = u1;
}

// all 4 layers' e2 in one pass over d2db. grid (96, 2)
__global__ void e2all_k(const float* __restrict__ d2db, const float* __restrict__ uvec,
                        float* __restrict__ e2all)
{
  __shared__ float us[1024];
  int t = threadIdx.x;
  for (int idx = t; idx < 1024; idx += 256)
    us[idx] = uvec[(idx >> 8) * 512 + 256 + (idx & 255)];
  __syncthreads();
  int m = blockIdx.x * 256 + t;
  int b = blockIdx.y;
  const float* xb = d2db + (ll)b * 6291456;
  float a[4] = {};
  for (int c = 0; c < 256; ++c) {
    float v = xb[(ll)c * 24576 + m];
#pragma unroll
    for (int g = 0; g < 4; ++g) a[g] = fmaf(v, us[g * 256 + c], a[g]);
  }
#pragma unroll
  for (int g = 0; g < 4; ++g) e2all[((ll)g * 2 + b) * 24576 + m] = a[g];
}

// gat attention (fused) + g accumulation:
// g[b][n][c] = at0*d3[n][c] + sum_l at[l+1]*d2db[b][c][n*8+l]
// att recomputed per block (4x redundant across c0, cheap). grid (48, 4, 2)
__global__ __launch_bounds__(256) void gat_g_k(
    const short* __restrict__ stb, const float* __restrict__ d2db,
    const float* __restrict__ uvec, const float* __restrict__ e2all,
    short* __restrict__ g, int gi)
{
  __shared__ float ush[512];
  __shared__ float attw[576];
  __shared__ float gtile[64 * 69];
  const int n0 = blockIdx.x * 64, c0 = blockIdx.y * 64, b = blockIdx.z;
  const int t = threadIdx.x;
  for (int idx = t; idx < 512; idx += 256) ush[idx] = uvec[gi * 512 + idx];
  __syncthreads();
  {
    const int q = t & 3, pl = t >> 2;
    const int n = n0 + pl;
    const short* xr = stb + (ll)(2 + b) * 786432 + (ll)n * 256 + q * 64;
    float a0 = 0.f, a1 = 0.f;
#pragma unroll
    for (int i = 0; i < 8; ++i) {
      s8v v8 = *(const s8v*)(xr + i * 8);
#pragma unroll
      for (int j = 0; j < 8; ++j) {
        float v = b2f(v8[j]);
        a0 = fmaf(v, ush[q * 64 + i * 8 + j], a0);
        a1 = fmaf(v, ush[256 + q * 64 + i * 8 + j], a1);
      }
    }
    a0 += __shfl_xor(a0, 1); a0 += __shfl_xor(a0, 2);
    a1 += __shfl_xor(a1, 1); a1 += __shfl_xor(a1, 2);
    if (q == 0) {
      float e[9];
      e[0] = a0 + a1;
      const float* e2b = e2all + ((ll)gi * 2 + b) * 24576 + (ll)n * 8;
#pragma unroll
      for (int l = 0; l < 8; ++l) e[l + 1] = a0 + e2b[l];
      float mx = -3.4e38f;
#pragma unroll
      for (int l = 0; l < 9; ++l) {
        e[l] = e[l] >= 0.f ? e[l] : 0.2f * e[l];
        mx = fmaxf(mx, e[l]);
      }
      float s = 0.f;
#pragma unroll
      for (int l = 0; l < 9; ++l) { e[l] = expf(e[l] - mx); s += e[l]; }
      float inv = 1.f / s;
#pragma unroll
      for (int l = 0; l < 9; ++l) attw[pl * 9 + l] = e[l] * inv;
    }
  }
  __syncthreads();
  const int nl = t >> 2, l2 = (t & 3) * 2;
  for (int cc = 0; cc < 64; ++cc) {
    const float* src = d2db + ((ll)b * 256 + c0 + cc) * 24576 + (ll)n0 * 8;
    float2 v = *(const float2*)(src + t * 2);
    float p = v.x * attw[nl * 9 + 1 + l2] + v.y * attw[nl * 9 + 2 + l2];
    p += __shfl_xor(p, 1);
    p += __shfl_xor(p, 2);
    if ((t & 3) == 0) gtile[nl * 69 + cc] = p;
  }
  __syncthreads();
#pragma unroll
  for (int i = 0; i < 4; ++i) {
    int n = (t >> 4) + i * 16;
    int cp = (t & 15) * 4;
    float at0 = attw[n * 9];
    const short* dr = stb + (ll)(2 + b) * 786432 + (ll)(n0 + n) * 256 + c0 + cp;
    uint2 dv = *(const uint2*)dr;
    float d0 = b2f((short)(dv.x & 0xffff)), d1 = b2f((short)(dv.x >> 16));
    float d2 = b2f((short)(dv.y & 0xffff)), d3v = b2f((short)(dv.y >> 16));
    uint2 ov;
    ov.x = pk2(gtile[n * 69 + cp] + at0 * d0, gtile[n * 69 + cp + 1] + at0 * d1);
    ov.y = pk2(gtile[n * 69 + cp + 2] + at0 * d2, gtile[n * 69 + cp + 3] + at0 * d3v);
    *(uint2*)(g + (ll)b * 786432 + (ll)(n0 + n) * 256 + c0 + cp) = ov;
  }
}

// ---------------- linear attention (h-planar channels) ----------------
// atomics directly into zero-init'd per-layer kv slot ([d][q]) + ksum
__global__ __launch_bounds__(256) void kv_partial_k(
    const short* __restrict__ qkv, float* __restrict__ kvat, float* __restrict__ ksat)
{
  __shared__ float ks[32][66];
  __shared__ float vs[32][66];
  const int p = blockIdx.x, h = blockIdx.y, z = blockIdx.z;
  const short* base = qkv + (ll)z * 2359296;
  const int t = threadIdx.x;
  const int tq = (t >> 4) * 4, tk = (t & 15) * 4;
  const int ml = t >> 3, d8 = (t & 7) * 8;
  float acc[4][4] = {};
  float ksl = 0.f;
  for (int sub = 0; sub < 8; ++sub) {
    int m0 = p * 256 + sub * 32;
    {
      const short* kr = base + (ll)(m0 + ml) * 768 + 256 + h * 64 + d8;
      s8v k8 = *(const s8v*)kr;
      s8v v8 = *(const s8v*)(kr + 256);
#pragma unroll
      for (int j = 0; j < 8; ++j) {
        float kvv = b2f(k8[j]);
        ks[ml][d8 + j] = kvv > 0.f ? kvv + 1.f : expf(kvv);  // elu+1
        vs[ml][d8 + j] = b2f(v8[j]);
      }
    }
    __syncthreads();
#pragma unroll 8
    for (int mm = 0; mm < 32; ++mm) {
      float vv[4], kk[4];
#pragma unroll
      for (int i = 0; i < 4; ++i) { vv[i] = vs[mm][tq + i]; kk[i] = ks[mm][tk + i]; }
#pragma unroll
      for (int i = 0; i < 4; ++i)
#pragma unroll
        for (int j = 0; j < 4; ++j)
          acc[i][j] = fmaf(vv[i], kk[j], acc[i][j]);
    }
    if (t < 64) {
#pragma unroll 8
      for (int mm = 0; mm < 32; ++mm) ksl += ks[mm][t];
    }
    __syncthreads();
  }
  float* kvz = kvat + ((ll)z * 4 + h) * 4096;
#pragma unroll
  for (int i = 0; i < 4; ++i)
#pragma unroll
    for (int j = 0; j < 4; ++j)
      atomicAdd(&kvz[(tk + j) * 64 + tq + i], acc[i][j]);   // [d][q]
  if (t < 64) atomicAdd(&ksat[(z * 4 + h) * 64 + t], ksl);
}

__global__ __launch_bounds__(256) void attn_out_k(
    const short* __restrict__ qkv, const float* __restrict__ kv,
    const float* __restrict__ ksum, short* __restrict__ obuf)
{
  __shared__ float qt[64][67];
  __shared__ float kvT[64][66];
  __shared__ float zsh[64];
  __shared__ float kss[64];
  const int n0 = blockIdx.x * 64, h = blockIdx.y, z = blockIdx.z;
  const int t = threadIdx.x;
  {
    int nl = t >> 3, d8 = (t & 7) * 8;
    const short* qr0 = qkv + (ll)z * 2359296 + (ll)(n0 + nl) * 768 + h * 64 + d8;
#pragma unroll
    for (int i = 0; i < 2; ++i) {
      const short* qr = qr0 + (ll)i * 32 * 768;
      s8v q8 = *(const s8v*)qr;
#pragma unroll
      for (int j = 0; j < 8; ++j) {
        float q = b2f(q8[j]);
        qt[nl + i * 32][d8 + j] = q > 0.f ? q + 1.f : expf(q);
      }
    }
  }
  {
    const float* kvb = kv + (ll)(z * 4 + h) * 4096;
#pragma unroll
    for (int i = 0; i < 16; ++i) {
      int idx = t + i * 256;
      kvT[idx >> 6][idx & 63] = kvb[idx];
    }
  }
  if (t < 64) kss[t] = ksum[(z * 4 + h) * 64 + t];
  __syncthreads();
  if (t < 64) {
    float s = 0.f;
    for (int d = 0; d < 64; ++d) s = fmaf(qt[t][d], kss[d], s);
    zsh[t] = 1.f / (s + 1e-6f);
  }
  __syncthreads();
  const int tn = t >> 4, tj = t & 15;
  float acc[4][4] = {};
  for (int d = 0; d < 64; ++d) {
    float av[4], bv[4];
#pragma unroll
    for (int i = 0; i < 4; ++i) av[i] = qt[tn * 4 + i][d];
    *(float4*)bv = *(const float4*)&kvT[d][tj * 4];
#pragma unroll
    for (int i = 0; i < 4; ++i)
#pragma unroll
      for (int j = 0; j < 4; ++j)
        acc[i][j] = fmaf(av[i], bv[j], acc[i][j]);
  }
#pragma unroll
  for (int i = 0; i < 4; ++i) {
    int n = n0 + tn * 4 + i;
    float zv = zsh[tn * 4 + i];
    uint2 o;
    o.x = pk2(acc[i][0] * zv, acc[i][1] * zv);
    o.y = pk2(acc[i][2] * zv, acc[i][3] * zv);
    *(uint2*)(obuf + (ll)z * 786432 + (ll)n * 256 + h * 64 + tj * 4) = o;
  }
}

// ---------------- instnorm apply (+relu); stats fused into mlp1 gemm ------
__global__ void in_apply_k(short* __restrict__ hid, const float* __restrict__ inat)
{
  int z = blockIdx.z, cg = blockIdx.y, nc = blockIdx.x;
  int t = threadIdx.x;
  int c = cg * 64 + (t & 63);
  float2 sq = *(const float2*)(inat + ((ll)(z * 512 + c) << 1));
  float mu = sq.x * (1.f / NPOS);
  float var = sq.y * (1.f / NPOS) - mu * mu;
  float rsig = rsqrtf(fmaxf(var, 0.f) + 1e-5f);
  short* base = hid + (ll)z * 1572864 + (ll)(nc * 384 + (t >> 6)) * 512 + c;
#pragma unroll 4
  for (int i = 0; i < 96; ++i) {
    float v = (b2f(base[(ll)i * 2048]) - mu) * rsig;
    base[(ll)i * 2048] = f2b(v > 0.f ? v : 0.f);
  }
}

// ---------------- final epilogue ----------------
__global__ void colstat_comb_k(const float* __restrict__ pmax, const float* __restrict__ psum,
                               float* __restrict__ cmax, float* __restrict__ csum)
{
  int m = blockIdx.x * 256 + threadIdx.x; int b = blockIdx.y;
  float M = -3.4e38f;
  for (int c = 0; c < 48; ++c) M = fmaxf(M, pmax[((ll)b * 48 + c) * NPOS + m]);
  float s = 0.f;
  for (int c = 0; c < 48; ++c)
    s += psum[((ll)b * 48 + c) * NPOS + m] * expf(pmax[((ll)b * 48 + c) * NPOS + m] - M);
  cmax[b * NPOS + m] = M; csum[b * NPOS + m] = s;
}

__global__ __launch_bounds__(256) void rowfix_k(
    float* __restrict__ S, const float* __restrict__ cmax, const float* __restrict__ csum,
    int* __restrict__ i0, float* __restrict__ m0)
{
  int n = blockIdx.x, b = blockIdx.y, t = threadIdx.x;
  float* row = S + (ll)b * 9437184 + (ll)n * NPOS;
  __shared__ float red[4];
  float v[12];
  float mx = -3.4e38f;
#pragma unroll
  for (int i = 0; i < 12; ++i) { v[i] = row[t + i * 256]; mx = fmaxf(mx, v[i]); }
#pragma unroll
  for (int off = 32; off > 0; off >>= 1) mx = fmaxf(mx, __shfl_down(mx, off));
  if ((t & 63) == 0) red[t >> 6] = mx;
  __syncthreads();
  float rm = fmaxf(fmaxf(red[0], red[1]), fmaxf(red[2], red[3]));
  __syncthreads();
  float s = 0.f;
#pragma unroll
  for (int i = 0; i < 12; ++i) s += expf(v[i] - rm);
  s = waveSum(s);
  if ((t & 63) == 0) red[t >> 6] = s;
  __syncthreads();
  float irs = 1.f / (red[0] + red[1] + red[2] + red[3]);
  float bv = -1.f; int bi = 0;
#pragma unroll
  for (int i = 0; i < 12; ++i) {
    int m = t + i * 256;
    float f = expf(2.f * v[i] - rm - cmax[b * NPOS + m]) * irs / csum[b * NPOS + m];
    row[m] = f;
    if (f > bv) { bv = f; bi = m; }
  }
  if (b == 0) {
#pragma unroll
    for (int off = 32; off > 0; off >>= 1) {
      float ov = __shfl_down(bv, off);
      int oi = __shfl_down(bi, off);
      if (ov > bv || (ov == bv && oi < bi)) { bv = ov; bi = oi; }
    }
    __shared__ float rv[4]; __shared__ int ri[4];
    if ((t & 63) == 0) { rv[t >> 6] = bv; ri[t >> 6] = bi; }
    __syncthreads();
    if (t == 0) {
      for (int w = 1; w < 4; ++w)
        if (rv[w] > bv || (rv[w] == bv && ri[w] < bi)) { bv = rv[w]; bi = ri[w]; }
      i0[n] = bi; m0[n] = bv;
    }
  }
}

__global__ void colamax_part_k(const float* __restrict__ Cf,
                               float* __restrict__ capv, int* __restrict__ capi)
{
  int m = blockIdx.x * 256 + threadIdx.x;
  int n0 = blockIdx.y * 128;
  float bv = -1.f; int bi = 0;
  for (int n = n0; n < n0 + 128; ++n) {
    float f = Cf[(ll)n * NPOS + m];
    if (f > bv) { bv = f; bi = n; }
  }
  capv[blockIdx.y * NPOS + m] = bv;
  capi[blockIdx.y * NPOS + m] = bi;
}

__global__ void colamax_comb_k(const float* __restrict__ capv, const int* __restrict__ capi,
                               int* __restrict__ i1)
{
  int m = blockIdx.x * 256 + threadIdx.x;
  float bv = -1.f; int bi = 0;
  for (int c = 0; c < 24; ++c) {
    float v = capv[c * NPOS + m];
    if (v > bv) { bv = v; bi = capi[c * NPOS + m]; }
  }
  i1[m] = bi;
}

__global__ void match0_k(const int* __restrict__ i0, const float* __restrict__ m0,
                         const int* __restrict__ i1, float* __restrict__ out)
{
  int n = blockIdx.x * 256 + threadIdx.x;
  int j = i0[n];
  bool mut = (i1[j] == n);
  float ms0 = mut ? m0[n] : 0.f;
  bool valid = mut && (ms0 > 0.2f);
  out[n] = valid ? (float)j : -1.f;
  out[6144 + n] = ms0;
}

__global__ void match1_k(const int* __restrict__ i0, const int* __restrict__ i1,
                         float* __restrict__ out)
{
  int m = blockIdx.x * 256 + threadIdx.x;
  int j = i1[m];
  bool mut = (i0[j] == m);
  float ms0v = out[6144 + j];
  float ind0v = out[j];
  float ms1 = mut ? ms0v : 0.f;
  bool valid1 = mut && (ind0v >= 0.f);
  out[3072 + m] = valid1 ? (float)j : -1.f;
  out[9216 + m] = ms1;
}

// ------------------------------------------------------------------
extern "C" void kernel_launch(void* const* d_in, const int* in_sizes, int n_in,
                              void* d_out, int out_size, void* d_ws, size_t ws_size,
                              hipStream_t stream)
{
  const float* desc2dq = (const float*)d_in[0];
  const float* desc3db = (const float*)d_in[1];
  const float* desc2db = (const float*)d_in[2];
  const float* projw = (const float*)d_in[3];
  const float* projb = (const float*)d_in[4];
  const float* mergew = (const float*)d_in[5];
  const float* mergeb = (const float*)d_in[6];
  const float* mlp1w = (const float*)d_in[7];
  const float* mlp1b = (const float*)d_in[8];
  const float* mlp2w = (const float*)d_in[9];
  const float* mlp2b = (const float*)d_in[10];
  const float* gatW = (const float*)d_in[11];
  const float* gata = (const float*)d_in[12];
  const float* finw = (const float*)d_in[13];
  const float* finb = (const float*)d_in[14];

  float* ws = (float*)d_ws;
  float* out = (float*)d_out;

  float* stf = ws + OFF_STF;
  short* stb = (short*)(ws + OFF_STB);
  short* qkv = (short*)(ws + OFF_QKV);
  short* msg = (short*)(ws + OFF_MSG);
  short* obuf = msg;
  short* hid = (short*)(ws + OFF_HID);
  short* wbf = (short*)(ws + OFF_WBF);
  short* projw_bf = wbf;
  short* mergewT_bf = wbf + 1572864;
  short* mlp1c_bf = wbf + 2097152;
  short* mlp2w_bf = wbf + 4194304;
  short* gatwT_bf = wbf + 5242880;
  short* finw_bf = wbf + 5505024;
  float* pbp = ws + OFF_PBP;
  float* uvec = ws + OFF_UVEC;
  float* e2all = ws + OFF_E2ALL;
  float* pmax = ws + OFF_PMAX;
  float* psum = ws + OFF_PSUM;
  float* cmax = ws + OFF_CMAX;
  float* csum = ws + OFF_CSUM;
  float* capv = ws + OFF_CAPV;
  int* capi = (int*)(ws + OFF_CAPI);
  int* i0 = (int*)(ws + OFF_I0);
  float* m0 = ws + OFF_M0;
  int* i1 = (int*)(ws + OFF_I1);
  short* m1b_bf = (short*)(ws + OFF_M1B);
  float* b1c = ws + OFF_B1C;
  float* inat = ws + OFF_INAT;
  float* svsq = ws + OFF_SVSQ;
  float* kvat = ws + OFF_KVAT;
  float* ksat = ws + OFF_KSAT;
  short* finbf = msg;                      // alias (obuf dead by then)

  // ---- init ----
  zero_k<<<564, 256, 0, stream>>>(inat, (int)ZERO_N);
  transpose_in_k<<<dim3(48, 4, 4), 256, 0, stream>>>(desc2dq, desc3db, stf, stb);
  projw_perm_k<<<6144, 256, 0, stream>>>(projw, projw_bf);
  pbp_k<<<24, 256, 0, stream>>>(projb, pbp);
  mergewT_k<<<dim3(4, 4, 8), 256, 0, stream>>>(mergew, mergewT_bf);
  f2b_split_k<<<1024, 256, 0, stream>>>(mlp1w, mlp1c_bf, m1b_bf);
  f2b_k<<<512, 256, 0, stream>>>(mlp2w, mlp2w_bf, 131072);
  gatw_t_k<<<dim3(4, 4, 4), 256, 0, stream>>>(gatW, gatwT_bf);
  f2b_k<<<32, 256, 0, stream>>>(finw, finw_bf, 8192);
  biasfold_k<<<64, 256, 0, stream>>>(mlp1w, mlp1b, mergeb, b1c);
  // M2[ai][o][p] = sum_c mlp1w[ai][o][256+c] * mergew[ai][c][cin(p)]
  bgemm_k<64, 128, 256, 0><<<dim3(2, 8, 8), 256, 0, stream>>>(
      m1b_bf, nullptr, 0, 256, 0, mergewT_bf, nullptr, nullptr,
      nullptr, mlp1c_bf + 256, nullptr, nullptr,
      512, 1.f, 131072, 0, 65536, 0, 0, 262144, 0, 0, 0, 7, 0, 0,
      nullptr, nullptr, 0);
  gat_prep_k<<<4, 256, 0, stream>>>(gatW, gata, uvec);
  e2all_k<<<dim3(96, 2), 256, 0, stream>>>(desc2db, uvec, e2all);

  auto attn_layer = [&](int ai, int cross) {
    const short* pw = projw_bf + (ll)ai * 196608;
    const float* pb = pbp + (ll)ai * 768;
    // qkv projection: one dispatch; for cross, blocks with bx<2 (q cols)
    // read the dq state (zaq=0) while k/v cols read the src state (za=2)
    bgemm_k<64, 128, 256, 0><<<dim3(6, 48, 4), 256, 0, stream>>>(
        stb, nullptr, 0, 256, 0, pw, pb, nullptr, nullptr, qkv, nullptr, nullptr,
        768, 1.f, 786432, 0, 0, 0, 0, 2359296, cross ? 2 : 0, 0, 0, 3,
        cross ? 2 : 0, 0,
        nullptr, nullptr, 0);
    kv_partial_k<<<dim3(12, 4, 4), 256, 0, stream>>>(
        qkv, kvat + (ll)ai * 65536, ksat + (ll)ai * 1024);
    attn_out_k<<<dim3(48, 4, 4), 256, 0, stream>>>(
        qkv, kvat + (ll)ai * 65536, ksat + (ll)ai * 1024, obuf);
    // merge folded into mlp1: hid = stb@W1a + obuf@M2 + b1c; instnorm stats fused
    bgemm_k<64, 128, 512, 2><<<dim3(4, 48, 4), 256, 0, stream>>>(
        stb, obuf, 256, 256, 256, mlp1c_bf + (ll)ai * 262144, b1c + (ll)ai * 512,
        nullptr, nullptr, hid, nullptr, nullptr,
        512, 1.f, 786432, 786432, 0, 0, 0, 1572864, 0, 0, 0, 3, 0, 0,
        inat + (ll)ai * 4096, nullptr, 0);
    in_apply_k<<<dim3(8, 8, 4), 256, 0, stream>>>(hid, inat + (ll)ai * 4096);
    bgemm_k<64, 64, 512, 0><<<dim3(4, 48, 4), 256, 0, stream>>>(
        hid, nullptr, 0, 512, 0, mlp2w_bf + (ll)ai * 131072, mlp2b + (ll)ai * 256,
        stf, stf, stb, nullptr, nullptr,
        256, 1.f, 1572864, 0, 0, 786432, 786432, 786432, 0, 0, 0, 3, 0, 0,
        nullptr, nullptr, 0);
  };

  auto gat_layer = [&](int gi) {
    gat_g_k<<<dim3(48, 4, 2), 256, 0, stream>>>(stb, desc2db, uvec, e2all, obuf, gi);
    bgemm_k<64, 64, 256, 0><<<dim3(4, 48, 2), 256, 0, stream>>>(
        obuf, nullptr, 0, 256, 0, gatwT_bf + (ll)gi * 65536, nullptr, nullptr,
        stf + (ll)2 * 786432, stb + (ll)2 * 786432, nullptr, nullptr,
        256, 1.f, 786432, 0, 0, 0, 786432, 786432, 0, 0, 1, 3, 0, 0,
        nullptr, nullptr, 0);
  };

  int ai = 0, gi = 0;
  for (int r = 0; r < 4; ++r) {
    gat_layer(gi); gi++;
    attn_layer(ai, 0); ai++;   // self
    attn_layer(ai, 1); ai++;   // cross
  }

  // final projection -> bf16; row sumsq fused (svsq)
  bgemm_k<64, 64, 256, 3><<<dim3(4, 48, 4), 256, 0, stream>>>(
      stb, nullptr, 0, 256, 0, finw_bf, finb, nullptr, nullptr, finbf, nullptr, nullptr,
      256, 1.f, 786432, 0, 0, 0, 0, 786432, 0, 0, 0, 3, 0, 0,
      svsq, nullptr, 0);

  // scores = 10 * norm(mq)[n] . norm(md)[m]; col softmax stats fused (pmax/psum)
  float* conf = out + 12288;
  bgemm_k<64, 128, 256, 1><<<dim3(24, 48, 2), 256, 0, stream>>>(
      finbf, nullptr, 0, 256, 0, finbf, nullptr, nullptr, conf, nullptr, svsq, svsq,
      3072, 10.f, 786432, 0, 786432, 0, 9437184, 0, 0, 2, 0, 3, 0, 0,
      pmax, psum, 1);

  colstat_comb_k<<<dim3(12, 2), 256, 0, stream>>>(pmax, psum, cmax, csum);
  rowfix_k<<<dim3(NPOS, 2), 256, 0, stream>>>(conf, cmax, csum, i0, m0);
  colamax_part_k<<<dim3(12, 24), 256, 0, stream>>>(conf, capv, capi);
  colamax_comb_k<<<12, 256, 0, stream>>>(capv, capi, i1);
  match0_k<<<12, 256, 0, stream>>>(i0, m0, i1, out);
  match1_k<<<12, 256, 0, stream>>>(i0, i1, out);
}